// Round 7
// baseline (52.977 us; speedup 1.0000x reference)
//
#include <hip/hip_runtime.h>

// YOLO decode: (32, 3*85, 64, 64) f32 -> (32, 3*64*64, 85) f32
// Persistent waves: each wave owns one grid row (4 tiles of 16 positions),
// grid = 1536 blocks = 6/CU -> fully co-resident, no dispatch churn.
// Register-double-buffered prefetch pipelines tile t+1 loads under tile t
// transform+store. Wave-private LDS transpose in output layout, no barrier.

#define NB    32
#define NA    3
#define ATTRS 85
#define HH    64
#define WW    64
#define HWSZ  (HH * WW)            // 4096
#define TPW   16                   // positions per tile
#define CHUNKS (ATTRS * (TPW / 4)) // 340 float4 chunks per tile = 5*64 + 20
#define WAVE_LDS (TPW * ATTRS)     // 1360 floats per wave

typedef float f32x4 __attribute__((ext_vector_type(4)));

__device__ __forceinline__ float fast_sigmoid(float x) {
    return __builtin_amdgcn_rcpf(1.0f + __expf(-x));
}

__global__ __launch_bounds__(256)
void yolo_decode_kernel(const float* __restrict__ in,
                        const float* __restrict__ anchors,
                        const int* __restrict__ imh,
                        const int* __restrict__ imw,
                        float* __restrict__ out)
{
    __shared__ float lds[4 * WAVE_LDS];   // 21760 B -> 7 blocks/CU

    const int tid  = threadIdx.x;
    const int wid  = tid >> 6;
    const int lane = tid & 63;
    float* __restrict__ wlds = lds + wid * WAVE_LDS;

    const int wjob = blockIdx.x * 4 + wid;   // 0 .. 6143: one grid row each
    const int ba   = wjob >> 6;              // b*3 + a
    const int row  = wjob & 63;
    const int b    = ba / NA;
    const int a    = ba - b * NA;

    const float stride_w = (float)(*imw) / (float)WW;
    const float stride_h = (float)(*imh) / (float)HH;
    const float aw = anchors[a * 2 + 0];
    const float ah = anchors[a * 2 + 1];
    const float gy = (float)row;

    const float* __restrict__ src =
        in + (size_t)ba * ATTRS * HWSZ + row * WW;   // start of this row
    float* __restrict__ dstw =
        out + ((size_t)ba * HWSZ + row * WW) * ATTRS;

    const bool tail = (lane < CHUNKS - 5 * 64);      // lane < 20

    // chunk index decode (same for every tile): i = k*64+lane
    // attr = i>>2, p4 = i&3
    f32x4 va[2][6];

    // ---- prime: load tile 0
#pragma unroll
    for (int k = 0; k < 5; ++k) {
        const int i = k * 64 + lane;
        va[0][k] = *(const f32x4*)(src + (i >> 2) * HWSZ + (i & 3) * 4);
    }
    if (tail) {
        const int i = 5 * 64 + lane;
        va[0][5] = *(const f32x4*)(src + (i >> 2) * HWSZ + (i & 3) * 4);
    }

#pragma unroll
    for (int t = 0; t < 4; ++t) {
        const int cur = t & 1;
        const int nxt = cur ^ 1;

        // ---- prefetch tile t+1 (independent of everything below)
        if (t < 3) {
            const float* __restrict__ s2 = src + (t + 1) * TPW;
#pragma unroll
            for (int k = 0; k < 5; ++k) {
                const int i = k * 64 + lane;
                va[nxt][k] = *(const f32x4*)(s2 + (i >> 2) * HWSZ + (i & 3) * 4);
            }
            if (tail) {
                const int i = 5 * 64 + lane;
                va[nxt][5] = *(const f32x4*)(s2 + (i >> 2) * HWSZ + (i & 3) * 4);
            }
        }

        // ---- transform tile t + scatter into output-layout LDS
        const int gx0 = t * TPW;
#pragma unroll
        for (int k = 0; k < 6; ++k) {
            if (k == 5 && !tail) break;
            const int i    = k * 64 + lane;
            const int attr = i >> 2;
            const int p4   = i & 3;
            float x[4] = {va[cur][k].x, va[cur][k].y, va[cur][k].z, va[cur][k].w};
            float r[4];
            if (attr >= 4) {
#pragma unroll
                for (int j = 0; j < 4; ++j)
                    r[j] = fast_sigmoid(x[j]);
            } else if (attr == 0) {
#pragma unroll
                for (int j = 0; j < 4; ++j)
                    r[j] = (fast_sigmoid(x[j]) + (float)(gx0 + p4 * 4 + j)) * stride_w;
            } else if (attr == 1) {
#pragma unroll
                for (int j = 0; j < 4; ++j)
                    r[j] = (fast_sigmoid(x[j]) + gy) * stride_h;
            } else if (attr == 2) {
#pragma unroll
                for (int j = 0; j < 4; ++j)
                    r[j] = __expf(x[j]) * aw;
            } else {
#pragma unroll
                for (int j = 0; j < 4; ++j)
                    r[j] = __expf(x[j]) * ah;
            }
#pragma unroll
            for (int j = 0; j < 4; ++j)
                wlds[(p4 * 4 + j) * ATTRS + attr] = r[j];
        }

        // ---- copy out: LDS already in output order, contiguous span
        float* __restrict__ dst = dstw + t * TPW * ATTRS;
#pragma unroll
        for (int k = 0; k < 5; ++k) {
            const int i = k * 64 + lane;
            *(f32x4*)(dst + i * 4) = *(const f32x4*)(wlds + i * 4);
        }
        if (tail) {
            const int i = 5 * 64 + lane;
            *(f32x4*)(dst + i * 4) = *(const f32x4*)(wlds + i * 4);
        }
    }
}

extern "C" void kernel_launch(void* const* d_in, const int* in_sizes, int n_in,
                              void* d_out, int out_size, void* d_ws, size_t ws_size,
                              hipStream_t stream) {
    const float* in      = (const float*)d_in[0];
    const float* anchors = (const float*)d_in[1];
    const int*   imh     = (const int*)d_in[2];
    const int*   imw     = (const int*)d_in[3];
    float* out = (float*)d_out;

    const int njobs   = NB * NA * HH;   // 6144 wave-jobs (one grid row each)
    const int nblocks = njobs / 4;      // 1536 blocks = 6 per CU
    yolo_decode_kernel<<<nblocks, 256, 0, stream>>>(in, anchors, imh, imw, out);
}

// Round 8
// 45.399 us; speedup vs baseline: 1.1669x; 1.1669x over previous
//
#include <hip/hip_runtime.h>

// YOLO decode: (32, 3*85, 64, 64) f32 -> (32, 3*64*64, 85) f32
// Wave-private LDS transpose in output layout; no block barrier.
// 512-thread blocks (8 waves, adjacent tiles) halve the dispatch count to
// test the CP launch-rate hypothesis while preserving the cache-line-sharing
// tile->wave mapping (R7 showed sequential tiles per wave re-fetch lines).

#define NB    32
#define NA    3
#define ATTRS 85
#define HH    64
#define WW    64
#define HWSZ  (HH * WW)        // 4096
#define TPW   16               // positions per wave-tile
#define TILES_PER_BA (HWSZ / TPW)   // 256
#define CHUNKS (ATTRS * (TPW / 4))  // 340 float4 chunks per tile = 5*64 + 20
#define WAVE_LDS (TPW * ATTRS)      // 1360 floats per wave
#define WAVES_PER_BLOCK 8

typedef float f32x4 __attribute__((ext_vector_type(4)));

__device__ __forceinline__ float fast_sigmoid(float x) {
    return __builtin_amdgcn_rcpf(1.0f + __expf(-x));
}

__global__ __launch_bounds__(512)
void yolo_decode_kernel(const float* __restrict__ in,
                        const float* __restrict__ anchors,
                        const int* __restrict__ imh,
                        const int* __restrict__ imw,
                        float* __restrict__ out)
{
    __shared__ float lds[WAVES_PER_BLOCK * WAVE_LDS];  // 43520 B -> 3 blocks/CU, 24 waves

    const int tid  = threadIdx.x;
    const int wid  = tid >> 6;
    const int lane = tid & 63;
    float* __restrict__ wlds = lds + wid * WAVE_LDS;

    const int wtile = blockIdx.x * WAVES_PER_BLOCK + wid;  // 0 .. 24575
    const int tile  = wtile & (TILES_PER_BA - 1);
    const int ba    = wtile >> 8;                // b*3 + a
    const int b     = ba / NA;
    const int a     = ba - b * NA;
    const int pos0  = tile * TPW;

    const float stride_w = (float)(*imw) / (float)WW;
    const float stride_h = (float)(*imh) / (float)HH;
    const float aw = anchors[a * 2 + 0];
    const float ah = anchors[a * 2 + 1];

    // tile never crosses a grid row (pos0 % 64 in {0,16,32,48})
    const float gy  = (float)(pos0 >> 6);
    const int   gx0 = pos0 & (WW - 1);

    const float* __restrict__ src =
        in + (size_t)(b * (NA * ATTRS) + a * ATTRS) * HWSZ + pos0;

    const bool tail = (lane < CHUNKS - 5 * 64);   // lane < 20

    // ---- load phase: all 6 loads issued up front
    f32x4 v[6];
#pragma unroll
    for (int k = 0; k < 5; ++k) {
        const int i = k * 64 + lane;
        v[k] = *(const f32x4*)(src + (i >> 2) * HWSZ + (i & 3) * 4);
    }
    if (tail) {
        const int i = 5 * 64 + lane;
        v[5] = *(const f32x4*)(src + (i >> 2) * HWSZ + (i & 3) * 4);
    }

    // ---- transform + scatter into output-layout LDS
#pragma unroll
    for (int k = 0; k < 6; ++k) {
        if (k == 5 && !tail) break;
        const int i    = k * 64 + lane;
        const int attr = i >> 2;
        const int p4   = i & 3;
        float x[4] = {v[k].x, v[k].y, v[k].z, v[k].w};
        float r[4];
        if (attr >= 4) {              // conf + classes: sigmoid
#pragma unroll
            for (int j = 0; j < 4; ++j)
                r[j] = fast_sigmoid(x[j]);
        } else if (attr == 0) {       // box x
#pragma unroll
            for (int j = 0; j < 4; ++j)
                r[j] = (fast_sigmoid(x[j]) + (float)(gx0 + p4 * 4 + j)) * stride_w;
        } else if (attr == 1) {       // box y
#pragma unroll
            for (int j = 0; j < 4; ++j)
                r[j] = (fast_sigmoid(x[j]) + gy) * stride_h;
        } else if (attr == 2) {       // box w
#pragma unroll
            for (int j = 0; j < 4; ++j)
                r[j] = __expf(x[j]) * aw;
        } else {                      // attr == 3: box h
#pragma unroll
            for (int j = 0; j < 4; ++j)
                r[j] = __expf(x[j]) * ah;
        }
#pragma unroll
        for (int j = 0; j < 4; ++j)
            wlds[(p4 * 4 + j) * ATTRS + attr] = r[j];
    }

    // ---- intra-wave only: compiler orders ds_write -> ds_read via lgkmcnt.
    // LDS holds the tile in exact output order -> pure vectorized copy out.
    float* __restrict__ dst =
        out + ((size_t)ba * HWSZ + pos0) * ATTRS;
#pragma unroll
    for (int k = 0; k < 5; ++k) {
        const int i = k * 64 + lane;
        *(f32x4*)(dst + i * 4) = *(const f32x4*)(wlds + i * 4);
    }
    if (tail) {
        const int i = 5 * 64 + lane;
        *(f32x4*)(dst + i * 4) = *(const f32x4*)(wlds + i * 4);
    }
}

extern "C" void kernel_launch(void* const* d_in, const int* in_sizes, int n_in,
                              void* d_out, int out_size, void* d_ws, size_t ws_size,
                              hipStream_t stream) {
    const float* in      = (const float*)d_in[0];
    const float* anchors = (const float*)d_in[1];
    const int*   imh     = (const int*)d_in[2];
    const int*   imw     = (const int*)d_in[3];
    float* out = (float*)d_out;

    const int nwaves  = NB * NA * TILES_PER_BA;        // 24576
    const int nblocks = nwaves / WAVES_PER_BLOCK;      // 3072
    yolo_decode_kernel<<<nblocks, 512, 0, stream>>>(in, anchors, imh, imw, out);
}

// Round 9
// 44.789 us; speedup vs baseline: 1.1828x; 1.0136x over previous
//
#include <hip/hip_runtime.h>

// YOLO decode: (32, 3*85, 64, 64) f32 -> (32, 3*64*64, 85) f32
// Block-cooperative: one block = one grid row (64 pos) of one (b,a).
// Phase 1: fully-contiguous 4KB load instructions (256B per attr-row
// segment, 4x larger than the old 64B segments), transform in registers,
// scatter to block LDS tile in output layout. Phase 2: contiguous copy out.

#define NB    32
#define NA    3
#define ATTRS 85
#define HH    64
#define WW    64
#define HWSZ  (HH * WW)              // 4096
#define ROW_F4  (ATTRS * (WW / 4))   // 1360 float4 units per row-slice
#define FULL_K  (ROW_F4 / 256)       // 5 full block-wide iterations
#define TAIL_N  (ROW_F4 - FULL_K * 256) // 80

typedef float f32x4 __attribute__((ext_vector_type(4)));

__device__ __forceinline__ float fast_sigmoid(float x) {
    return __builtin_amdgcn_rcpf(1.0f + __expf(-x));
}

__global__ __launch_bounds__(256)
void yolo_decode_kernel(const float* __restrict__ in,
                        const float* __restrict__ anchors,
                        const int* __restrict__ imh,
                        const int* __restrict__ imw,
                        float* __restrict__ out)
{
    __shared__ float lds[WW * ATTRS];   // 21760 B -> 7 blocks/CU

    const int tid = threadIdx.x;
    const int bid = blockIdx.x;          // 0 .. 6143
    const int ba  = bid >> 6;            // b*3 + a
    const int row = bid & 63;
    const int b   = ba / NA;
    const int a   = ba - b * NA;

    const float stride_w = (float)(*imw) / (float)WW;
    const float stride_h = (float)(*imh) / (float)HH;
    const float aw = anchors[a * 2 + 0];
    const float ah = anchors[a * 2 + 1];
    const float gy = (float)row;

    const float* __restrict__ src =
        in + (size_t)ba * ATTRS * HWSZ + row * WW;   // this row's slice

    const bool tail = (tid < TAIL_N);

    // ---- phase 1: contiguous loads (4KB / instruction), transform, scatter
    // unit u: attr = u>>4 (uniform per 16 threads), p4 = u&15, pos = p4*4+j
    f32x4 v[FULL_K + 1];
#pragma unroll
    for (int k = 0; k < FULL_K; ++k) {
        const int u = k * 256 + tid;
        v[k] = *(const f32x4*)(src + (u >> 4) * HWSZ + (u & 15) * 4);
    }
    if (tail) {
        const int u = FULL_K * 256 + tid;
        v[FULL_K] = *(const f32x4*)(src + (u >> 4) * HWSZ + (u & 15) * 4);
    }

#pragma unroll
    for (int k = 0; k <= FULL_K; ++k) {
        if (k == FULL_K && !tail) break;
        const int u    = k * 256 + tid;
        const int attr = u >> 4;
        const int p4   = u & 15;
        float x[4] = {v[k].x, v[k].y, v[k].z, v[k].w};
        float r[4];
        if (attr >= 4) {              // conf + classes: sigmoid
#pragma unroll
            for (int j = 0; j < 4; ++j)
                r[j] = fast_sigmoid(x[j]);
        } else if (attr == 0) {       // box x: gx = p4*4+j
#pragma unroll
            for (int j = 0; j < 4; ++j)
                r[j] = (fast_sigmoid(x[j]) + (float)(p4 * 4 + j)) * stride_w;
        } else if (attr == 1) {       // box y
#pragma unroll
            for (int j = 0; j < 4; ++j)
                r[j] = (fast_sigmoid(x[j]) + gy) * stride_h;
        } else if (attr == 2) {       // box w
#pragma unroll
            for (int j = 0; j < 4; ++j)
                r[j] = __expf(x[j]) * aw;
        } else {                      // attr == 3: box h
#pragma unroll
            for (int j = 0; j < 4; ++j)
                r[j] = __expf(x[j]) * ah;
        }
#pragma unroll
        for (int j = 0; j < 4; ++j)
            lds[(p4 * 4 + j) * ATTRS + attr] = r[j];
    }

    __syncthreads();

    // ---- phase 2: LDS tile is the output row span, contiguous copy out
    float* __restrict__ dst = out + ((size_t)ba * HWSZ + row * WW) * ATTRS;
#pragma unroll
    for (int k = 0; k < FULL_K; ++k) {
        const int u = k * 256 + tid;
        *(f32x4*)(dst + u * 4) = *(const f32x4*)(lds + u * 4);
    }
    if (tail) {
        const int u = FULL_K * 256 + tid;
        *(f32x4*)(dst + u * 4) = *(const f32x4*)(lds + u * 4);
    }
}

extern "C" void kernel_launch(void* const* d_in, const int* in_sizes, int n_in,
                              void* d_out, int out_size, void* d_ws, size_t ws_size,
                              hipStream_t stream) {
    const float* in      = (const float*)d_in[0];
    const float* anchors = (const float*)d_in[1];
    const int*   imh     = (const int*)d_in[2];
    const int*   imw     = (const int*)d_in[3];
    float* out = (float*)d_out;

    const int nblocks = NB * NA * HH;   // 6144 blocks: one grid row each
    yolo_decode_kernel<<<nblocks, 256, 0, stream>>>(in, anchors, imh, imw, out);
}